// Round 1
// baseline (134.534 us; speedup 1.0000x reference)
//
#include <hip/hip_runtime.h>

typedef __attribute__((ext_vector_type(8)))  short bf16x8;
typedef __attribute__((ext_vector_type(4)))  float f32x4;
typedef __attribute__((ext_vector_type(16))) float f32x16;
typedef __attribute__((ext_vector_type(4)))  unsigned u32x4;

#define B_  2
#define S_  2048
#define H_  16
#define D_  64
#define E_  1024
#define M_  (B_*S_)

__device__ __forceinline__ float bf2f(unsigned short u){
  unsigned x = ((unsigned)u) << 16;
  return __builtin_bit_cast(float, x);
}
__device__ __forceinline__ unsigned short f2bf(float f){
  unsigned x = __builtin_bit_cast(unsigned, f);
  x += 0x7fffu + ((x >> 16) & 1u);
  return (unsigned short)(x >> 16);
}
__device__ __forceinline__ unsigned pack2bf(float lo, float hi){
  return ((unsigned)f2bf(hi) << 16) | (unsigned)f2bf(lo);
}

#define GLD16(gp, lp) __builtin_amdgcn_global_load_lds( \
    (const __attribute__((address_space(1))) unsigned*)(gp), \
    (__attribute__((address_space(3))) unsigned*)(lp), 16, 0, 0)

// ---------------- RoPE cos/sin table (double-precision trig) ----------------
__global__ __launch_bounds__(256) void k_rope_table(float* ct, float* st){
  int i = blockIdx.x*256 + threadIdx.x;   // 0 .. 2048*64-1
  int s = i >> 6, j = i & 63;
  int f = j & 31;                          // cos/sin identical for d and d+32
  double invf = pow(10000.0, -(double)f / 32.0);
  double ph = (double)s * invf;
  ct[i] = (float)cos(ph);
  st[i] = (float)sin(ph);
}

// ---------------- x fp32 -> bf16 ----------------
__global__ __launch_bounds__(256) void k_cvt(const float* __restrict__ in, short* __restrict__ out){
  int i = (blockIdx.x*256 + threadIdx.x)*4;
  float4 v = *(const float4*)(in + i);
  short r0 = (short)f2bf(v.x), r1 = (short)f2bf(v.y), r2 = (short)f2bf(v.z), r3 = (short)f2bf(v.w);
  typedef __attribute__((ext_vector_type(4))) short s16x4;
  s16x4 o = { r0, r1, r2, r3 };
  *(s16x4*)(out + i) = o;
}

// ---------------- W (K x N) fp32 -> W^T (N x K) bf16, 3 weights ----------------
__global__ __launch_bounds__(256) void k_wt(const float* __restrict__ Wq, const float* __restrict__ Wk,
                                            const float* __restrict__ Wv, short* __restrict__ wt){
  const float* W = blockIdx.z==0 ? Wq : (blockIdx.z==1 ? Wk : Wv);
  short* out = wt + (size_t)blockIdx.z*E_*E_;
  __shared__ short tile[64][72];
  int nb = blockIdx.x*64, kb = blockIdx.y*64;
  int t = threadIdx.x;
  {
    int r = t>>2, c0 = (t&3)*16;                     // k-row r, n-cols c0..c0+15
    const float* src = W + (size_t)(kb+r)*E_ + nb + c0;
    #pragma unroll
    for(int i=0;i<4;i++){
      float4 v = *(const float4*)(src + i*4);
      tile[r][c0+i*4+0] = (short)f2bf(v.x);
      tile[r][c0+i*4+1] = (short)f2bf(v.y);
      tile[r][c0+i*4+2] = (short)f2bf(v.z);
      tile[r][c0+i*4+3] = (short)f2bf(v.w);
    }
  }
  __syncthreads();
  {
    int n = t>>2, k0 = (t&3)*16;
    short* dst = out + (size_t)(nb+n)*E_ + kb + k0;
    bf16x8 o0, o1;
    #pragma unroll
    for(int i=0;i<8;i++){ o0[i] = tile[k0+i][n]; o1[i] = tile[k0+8+i][n]; }
    *(bf16x8*)dst = o0;
    *(bf16x8*)(dst+8) = o1;
  }
}

// ---------------- QKV projection GEMM: [4096,1024] x [1024,1024] + bias -> bf16 ----------------
__global__ __launch_bounds__(256) void k_gemm(const short* __restrict__ A, const short* __restrict__ WT,
                                              const float* __restrict__ biasq, const float* __restrict__ biask,
                                              const float* __restrict__ biasv,
                                              short* __restrict__ oq, short* __restrict__ ok, short* __restrict__ ov){
  const int z = blockIdx.z;
  const short* Bw = WT + (size_t)z*E_*E_;
  const float* bias = z==0 ? biasq : (z==1 ? biask : biasv);
  short* out = z==0 ? oq : (z==1 ? ok : ov);
  __shared__ short As[128*32];
  __shared__ short Bs[128*32];
  const int t = threadIdx.x, lane = t & 63, wid = t >> 6;
  const int mb = blockIdx.x*128, nb = blockIdx.y*128;
  const int wm = (wid>>1)*64, wn = (wid&1)*64;
  f32x4 acc[4][4] = {};
  for(int kt=0; kt<E_/32; kt++){
    __syncthreads();
    {
      int f0 = t, f1 = t + 256;
      GLD16(A  + (size_t)(mb + (f0>>2))*E_ + kt*32 + (f0&3)*8, &As[f0*8]);
      GLD16(A  + (size_t)(mb + (f1>>2))*E_ + kt*32 + (f1&3)*8, &As[f1*8]);
      GLD16(Bw + (size_t)(nb + (f0>>2))*E_ + kt*32 + (f0&3)*8, &Bs[f0*8]);
      GLD16(Bw + (size_t)(nb + (f1>>2))*E_ + kt*32 + (f1&3)*8, &Bs[f1*8]);
    }
    __syncthreads();
    bf16x8 af[4], bfv[4];
    #pragma unroll
    for(int mf=0; mf<4; mf++)
      af[mf] = *(const bf16x8*)&As[(wm + mf*16 + (lane&15))*32 + (lane>>4)*8];
    #pragma unroll
    for(int nf=0; nf<4; nf++)
      bfv[nf] = *(const bf16x8*)&Bs[(wn + nf*16 + (lane&15))*32 + (lane>>4)*8];
    #pragma unroll
    for(int mf=0; mf<4; mf++)
      #pragma unroll
      for(int nf=0; nf<4; nf++)
        acc[mf][nf] = __builtin_amdgcn_mfma_f32_16x16x32_bf16(af[mf], bfv[nf], acc[mf][nf], 0, 0, 0);
  }
  const int col16 = lane & 15, rg = lane >> 4;
  float bvs[4];
  #pragma unroll
  for(int nf=0; nf<4; nf++) bvs[nf] = bias[nb + wn + nf*16 + col16];
  #pragma unroll
  for(int mf=0; mf<4; mf++)
    #pragma unroll
    for(int nf=0; nf<4; nf++)
      #pragma unroll
      for(int r=0; r<4; r++){
        int row = mb + wm + mf*16 + rg*4 + r;
        int col = nb + wn + nf*16 + col16;
        out[(size_t)row*E_ + col] = (short)f2bf(acc[mf][nf][r] + bvs[nf]);
      }
}

// ---------------- RoPE in-place on q (with 0.125 fold) and k ----------------
__global__ __launch_bounds__(256) void k_rope(short* __restrict__ qp, short* __restrict__ kp,
                                              const float* __restrict__ ct, const float* __restrict__ st){
  short* p = blockIdx.y ? kp : qp;
  const float sc = blockIdx.y ? 1.f : 0.125f;    // fold 1/sqrt(D) into q
  const int row = blockIdx.x;                    // 0..4095 = b*2048+s
  const int t = threadIdx.x;
  const int h = t >> 4, j2 = (t & 15)*2;
  short* base = p + (size_t)row*E_ + h*D_;
  const float* cb = ct + (size_t)(row & (S_-1))*D_ + j2;
  const float* sb = st + (size_t)(row & (S_-1))*D_ + j2;
  float c0 = cb[0], c1 = cb[1], s0 = sb[0], s1 = sb[1];
  int lo = *(int*)(base + j2);
  int hi = *(int*)(base + j2 + 32);
  float x0 = bf2f((unsigned short)(lo & 0xffff)), x1 = bf2f((unsigned short)((unsigned)lo >> 16));
  float y0 = bf2f((unsigned short)(hi & 0xffff)), y1 = bf2f((unsigned short)((unsigned)hi >> 16));
  float r0 = (x0*c0 - y0*s0)*sc, r1 = (x1*c1 - y1*s1)*sc;
  float r2 = (y0*c0 + x0*s0)*sc, r3 = (y1*c1 + x1*s1)*sc;
  *(int*)(base + j2)      = (int)pack2bf(r0, r1);
  *(int*)(base + j2 + 32) = (int)pack2bf(r2, r3);
}

// ---------------- V -> V^T per (b,h): [S][D] -> [D][S] bf16 ----------------
__global__ __launch_bounds__(256) void k_vt(const short* __restrict__ v, short* __restrict__ vt){
  __shared__ short tl[64][72];
  const int b = blockIdx.z, h = blockIdx.y, s0 = blockIdx.x*64;
  const int t = threadIdx.x;
  {
    int r = t>>2, c0 = (t&3)*16;
    const short* src = v + ((size_t)(b*S_ + s0 + r)*H_ + h)*D_ + c0;
    *(bf16x8*)&tl[r][c0]   = *(const bf16x8*)src;
    *(bf16x8*)&tl[r][c0+8] = *(const bf16x8*)(src+8);
  }
  __syncthreads();
  {
    int d = t>>2, t0 = (t&3)*16;
    short* dst = vt + ((size_t)(b*H_ + h)*D_ + d)*S_ + s0 + t0;
    bf16x8 o0, o1;
    #pragma unroll
    for(int i=0;i<8;i++){ o0[i] = tl[t0+i][d]; o1[i] = tl[t0+8+i][d]; }
    *(bf16x8*)dst = o0;
    *(bf16x8*)(dst+8) = o1;
  }
}

// ---------------- Flash attention: swapped QK^T, 32x32x16 MFMA ----------------
__global__ __launch_bounds__(256) void k_attn(
    const short* __restrict__ qg, const short* __restrict__ kg,
    const short* __restrict__ vtg, const float* __restrict__ mask,
    float* __restrict__ outg){
  __shared__ short Ks[64*72];   // K tile [key][d], pad-72 rows (144B stride)
  __shared__ short Vs[64*72];   // V^T tile [d][key]
  const int b = blockIdx.z, h = blockIdx.y;
  const int t = threadIdx.x, wid = t>>6, lane = t&63;
  const int l31 = lane & 31, hl = lane >> 5;
  const int qw = blockIdx.x*128 + wid*32;

  bf16x8 qf[4];
  {
    const short* qb = qg + ((size_t)(b*S_ + qw + l31)*H_ + h)*D_;
    #pragma unroll
    for(int dk=0; dk<4; dk++)
      qf[dk] = *(const bf16x8*)(qb + dk*16 + hl*8);
  }
  f32x16 O0 = {}, O1 = {};
  float m_run = -1e30f, l_run = 0.f;
  const float* mrow = mask + (size_t)b*S_;

  for(int kb=0; kb<S_/64; kb++){
    __syncthreads();
    {
      const int rr = t>>3, ch = t&7;
      const short* ksrc = kg + ((size_t)(b*S_ + kb*64 + rr)*H_ + h)*D_ + ch*8;
      bf16x8 ka = *(const bf16x8*)ksrc;
      bf16x8 kc = *(const bf16x8*)(ksrc + 32*H_*D_);
      const short* vsrc = vtg + ((size_t)(b*H_ + h)*D_ + rr)*S_ + kb*64 + ch*8;
      bf16x8 va = *(const bf16x8*)vsrc;
      bf16x8 vc = *(const bf16x8*)(vsrc + 32*S_);
      *(bf16x8*)&Ks[rr*72 + ch*8] = ka;
      *(bf16x8*)&Ks[(rr+32)*72 + ch*8] = kc;
      *(bf16x8*)&Vs[rr*72 + ch*8] = va;
      *(bf16x8*)&Vs[(rr+32)*72 + ch*8] = vc;
    }
    __syncthreads();

    // S^T = K . Q^T : lane holds col q=l31; rows = keys
    f32x16 s0 = {}, s1 = {};
    #pragma unroll
    for(int dk=0; dk<4; dk++){
      bf16x8 kf0 = *(const bf16x8*)&Ks[(l31)*72 + dk*16 + hl*8];
      bf16x8 kf1 = *(const bf16x8*)&Ks[(32+l31)*72 + dk*16 + hl*8];
      s0 = __builtin_amdgcn_mfma_f32_32x32x16_bf16(kf0, qf[dk], s0, 0,0,0);
      s1 = __builtin_amdgcn_mfma_f32_32x32x16_bf16(kf1, qf[dk], s1, 0,0,0);
    }
    // + mask (broadcast over q); reg r=a+4*bb -> key = a + 8*bb + 4*hl (+32 for s1)
    {
      const float* mt = mrow + kb*64;
      #pragma unroll
      for(int bb=0; bb<4; bb++){
        f32x4 mv0 = *(const f32x4*)(mt + bb*8 + hl*4);
        f32x4 mv1 = *(const f32x4*)(mt + 32 + bb*8 + hl*4);
        #pragma unroll
        for(int a=0; a<4; a++){ s0[bb*4+a] += mv0[a]; s1[bb*4+a] += mv1[a]; }
      }
    }
    // row max over 64 keys: 31 in-lane + cross-half
    float tm = s0[0];
    #pragma unroll
    for(int i=1;i<16;i++) tm = fmaxf(tm, s0[i]);
    #pragma unroll
    for(int i=0;i<16;i++) tm = fmaxf(tm, s1[i]);
    tm = fmaxf(tm, __shfl_xor(tm, 32));

    if(__any(tm > m_run + 8.f)){             // defer-max rescale
      float m_new = fmaxf(m_run, tm);
      float sc = __expf(m_run - m_new);
      m_run = m_new;
      l_run *= sc;
      #pragma unroll
      for(int bb=0; bb<4; bb++)
        #pragma unroll
        for(int a=0; a<4; a++){
          float srow = __shfl(sc, a + 8*bb + 4*hl);  // O rows differ from state lanes
          O0[bb*4+a] *= srow;
          O1[bb*4+a] *= srow;
        }
    }
    #pragma unroll
    for(int i=0;i<16;i++){ s0[i] = __expf(s0[i] - m_run); s1[i] = __expf(s1[i] - m_run); }
    float ls = 0.f;
    #pragma unroll
    for(int i=0;i<16;i++) ls += s0[i] + s1[i];
    ls += __shfl_xor(ls, 32);
    l_run += ls;

    // pack P to bf16 words; chunk c: keys 8c + {0..3} + 4*hl
    unsigned w0a[8], w1a[8];
    #pragma unroll
    for(int c=0;c<8;c++){
      float p0 = (c & 4) ? s1[(c&3)*4+0] : s0[(c&3)*4+0];
      float p1 = (c & 4) ? s1[(c&3)*4+1] : s0[(c&3)*4+1];
      float p2 = (c & 4) ? s1[(c&3)*4+2] : s0[(c&3)*4+2];
      float p3 = (c & 4) ? s1[(c&3)*4+3] : s0[(c&3)*4+3];
      w0a[c] = pack2bf(p0, p1);
      w1a[c] = pack2bf(p2, p3);
    }
    // PV: A = P (row q=l31, k = hl*8+j within 16-key slice), B = V^T rows
    #pragma unroll
    for(int ksl=0; ksl<4; ksl++){
      unsigned oA = hl ? w0a[2*ksl+1] : w0a[2*ksl];
      unsigned oB = hl ? w1a[2*ksl+1] : w1a[2*ksl];
      unsigned sA = hl ? w0a[2*ksl]   : w0a[2*ksl+1];
      unsigned sB = hl ? w1a[2*ksl]   : w1a[2*ksl+1];
      unsigned rA = (unsigned)__shfl_xor((int)sA, 32);
      unsigned rB = (unsigned)__shfl_xor((int)sB, 32);
      u32x4 pw = { hl ? rA : oA, hl ? rB : oB, hl ? oA : rA, hl ? oB : rB };
      bf16x8 pf = __builtin_bit_cast(bf16x8, pw);
      bf16x8 vf0 = *(const bf16x8*)&Vs[(l31)*72 + ksl*16 + hl*8];
      bf16x8 vf1 = *(const bf16x8*)&Vs[(32+l31)*72 + ksl*16 + hl*8];
      O0 = __builtin_amdgcn_mfma_f32_32x32x16_bf16(pf, vf0, O0, 0,0,0);
      O1 = __builtin_amdgcn_mfma_f32_32x32x16_bf16(pf, vf1, O1, 0,0,0);
    }
  }
  float linv = 1.f / l_run;
  #pragma unroll
  for(int bb=0; bb<4; bb++)
    #pragma unroll
    for(int a=0; a<4; a++){
      float li = __shfl(linv, a + 8*bb + 4*hl);
      int qrow = qw + a + 8*bb + 4*hl;
      float* op = outg + ((size_t)(b*S_ + qrow)*H_ + h)*D_;
      op[l31]      = O0[bb*4+a] * li;
      op[32 + l31] = O1[bb*4+a] * li;
    }
}

extern "C" void kernel_launch(void* const* d_in, const int* in_sizes, int n_in,
                              void* d_out, int out_size, void* d_ws, size_t ws_size,
                              hipStream_t stream){
  (void)in_sizes; (void)n_in; (void)out_size; (void)ws_size;
  const float* x    = (const float*)d_in[0];
  const float* mask = (const float*)d_in[1];
  const float* Wq   = (const float*)d_in[2];
  const float* bq   = (const float*)d_in[3];
  const float* Wk   = (const float*)d_in[4];
  const float* bk   = (const float*)d_in[5];
  const float* Wv   = (const float*)d_in[6];
  const float* bv   = (const float*)d_in[7];
  float* out = (float*)d_out;
  char* ws = (char*)d_ws;
  // ws layout (39 MB): tables 1MB | xb 8MB (reused as v_T) | wt 6MB | q 8MB | k 8MB | v 8MB
  float* cost = (float*)ws;                          // 512KB
  float* sint = (float*)(ws + (512u<<10));           // 512KB
  short* xb   = (short*)(ws + (1u<<20));             // 8MB  (x bf16; later aliased by v_T)
  short* wt   = (short*)(ws + (9u<<20));             // 6MB
  short* qb   = (short*)(ws + (15u<<20));            // 8MB
  short* kb   = (short*)(ws + (23u<<20));            // 8MB
  short* vb   = (short*)(ws + (31u<<20));            // 8MB
  short* vtb  = xb;                                  // alias: xb dead after GEMM

  k_rope_table<<<dim3(512), dim3(256), 0, stream>>>(cost, sint);
  k_cvt<<<dim3(4096), dim3(256), 0, stream>>>(x, xb);
  k_wt<<<dim3(16,16,3), dim3(256), 0, stream>>>(Wq, Wk, Wv, wt);
  k_gemm<<<dim3(32,8,3), dim3(256), 0, stream>>>(xb, wt, bq, bk, bv, qb, kb, vb);
  k_rope<<<dim3(4096,2), dim3(256), 0, stream>>>(qb, kb, cost, sint);
  k_vt<<<dim3(32,16,2), dim3(256), 0, stream>>>(vb, vtb);
  k_attn<<<dim3(16,16,2), dim3(256), 0, stream>>>(qb, kb, vtb, mask, out);
}